// Round 4
// baseline (518.837 us; speedup 1.0000x reference)
//
#include <hip/hip_runtime.h>
#include <math.h>

#define L_  12
#define B_  32
#define H_  12
#define N1_ 197
#define D_  768
#define HD_ 64
#define R_  19

#define K1_FULL_ROWS  69344            // 11 layers * 32 b * 197 rows
#define K1_ROWS       69376            // + 32 layer-11 row-0 rows
#define K1_BLOCKS     (K1_ROWS / 4)    // 17344
#define QKV_TILES     900              // 50 x 18 tiles (M=6304, N=2304)
#define MEGA_BLOCKS   (K1_BLOCKS + QKV_TILES)   // 18244

typedef __attribute__((ext_vector_type(8))) short short8;
typedef __attribute__((ext_vector_type(4))) float f32x4;

// ---------------------------------------------------------------------------
// f32 -> bf16 hi/lo split (in-register). hi = rn(f), lo = rn(f - hi).
// hi*hi + hi*lo + lo*hi reproduces the f32 product to ~2^-17 relative.
// ---------------------------------------------------------------------------
__device__ inline ushort f2bf_rn(float f) {
  unsigned u = __float_as_uint(f);
  unsigned r = (u + 0x7FFFu + ((u >> 16) & 1u)) >> 16;
  return (ushort)r;
}
__device__ inline float bf2f(ushort h) { return __uint_as_float((unsigned)h << 16); }
__device__ inline void cvt4(float4 f, ushort4& h, ushort4& l) {
  h.x = f2bf_rn(f.x); l.x = f2bf_rn(f.x - bf2f(h.x));
  h.y = f2bf_rn(f.y); l.y = f2bf_rn(f.y - bf2f(h.y));
  h.z = f2bf_rn(f.z); l.z = f2bf_rn(f.z - bf2f(h.z));
  h.w = f2bf_rn(f.w); l.w = f2bf_rn(f.w - bf2f(h.w));
}

// ---------------------------------------------------------------------------
// Split-bf16 MFMA GEMM body, f32 inputs converted in-register at staging.
// C[m,n] = sum_k A[row(m),k] * W[n,k] (+bias[n]);  row(m)=gidx?gidx[m]:m;
// W row n comes from W{0,1,2}[n % 768] with sel = n/768 (weights are 768xK).
// BK=32, 256 threads = 4 waves (2x2). mfma_f32_16x16x32_bf16:
//   A/B frag: row = lane&15, k = 8*(lane>>4)+j  (contiguous -> ds_read_b128)
//   C/D:      col = lane&15, row = 4*(lane>>4)+reg   [m89-verified, R2/R3-passed]
// LDS row stride 40 bf16 (80B): 2-way bank aliasing = free (m136).
// ---------------------------------------------------------------------------
#define PK 40
template <int BM, int BN, int MF, int NF>
__device__ __forceinline__ void gemm_body(int bm, int bn,
                                          const float* __restrict__ A,
                                          const int* __restrict__ gidx,
                                          const float* __restrict__ W0,
                                          const float* __restrict__ W1,
                                          const float* __restrict__ W2,
                                          const float* __restrict__ bias,
                                          float* __restrict__ C,
                                          int M, int K, int ldc) {
  __shared__ __attribute__((aligned(16))) ushort As[2][BM][PK];
  __shared__ __attribute__((aligned(16))) ushort Bs[2][BN][PK];
  constexpr int TPRA = 256 / BM;   // threads per A row
  constexpr int EPTA = 32 / TPRA;  // f32 elems per thread per tile
  constexpr int NA4  = EPTA / 4;   // float4 loads
  constexpr int TPRB = 256 / BN;
  constexpr int EPTB = 32 / TPRB;
  constexpr int NB4  = EPTB / 4;

  int tid  = threadIdx.x;
  int lane = tid & 63, wid = tid >> 6;
  int wr = wid >> 1, wc = wid & 1;
  int lr = lane & 15, lk = lane >> 4;

  int arow_s = tid / TPRA;
  int akoff  = (tid % TPRA) * EPTA;
  int ar = bm * BM + arow_s; if (ar >= M) ar = M - 1;
  int asrc = gidx ? gidx[ar] : ar;
  const float* ap = A + (size_t)asrc * K + akoff;

  int brow_s = tid / TPRB;
  int bkoff  = (tid % TPRB) * EPTB;
  int wrow   = bn * BN + brow_s;
  int sel    = wrow / 768; if (sel > 2) sel = 2;
  const float* Wb = (sel == 0) ? W0 : (sel == 1) ? W1 : W2;
  const float* wp = Wb + (size_t)(wrow - sel * 768) * K + bkoff;

  f32x4 acc[MF][NF] = {};

  float4 pa[NA4], pb[NB4];
#pragma unroll
  for (int u = 0; u < NA4; ++u) pa[u] = *(const float4*)(ap + u * 4);
#pragma unroll
  for (int u = 0; u < NB4; ++u) pb[u] = *(const float4*)(wp + u * 4);

  for (int k0 = 0; k0 < K; k0 += 32) {
#pragma unroll
    for (int u = 0; u < NA4; ++u) {
      ushort4 h, l; cvt4(pa[u], h, l);
      *(ushort4*)&As[0][arow_s][akoff + u * 4] = h;
      *(ushort4*)&As[1][arow_s][akoff + u * 4] = l;
    }
#pragma unroll
    for (int u = 0; u < NB4; ++u) {
      ushort4 h, l; cvt4(pb[u], h, l);
      *(ushort4*)&Bs[0][brow_s][bkoff + u * 4] = h;
      *(ushort4*)&Bs[1][brow_s][bkoff + u * 4] = l;
    }
    __syncthreads();

    int kn = k0 + 32;
    if (kn < K) {
#pragma unroll
      for (int u = 0; u < NA4; ++u) pa[u] = *(const float4*)(ap + kn + u * 4);
#pragma unroll
      for (int u = 0; u < NB4; ++u) pb[u] = *(const float4*)(wp + kn + u * 4);
    }

    short8 af[2][MF], bf[2][NF];
#pragma unroll
    for (int m = 0; m < MF; ++m) {
      af[0][m] = *(const short8*)&As[0][wr * (BM / 2) + m * 16 + lr][lk * 8];
      af[1][m] = *(const short8*)&As[1][wr * (BM / 2) + m * 16 + lr][lk * 8];
    }
#pragma unroll
    for (int n = 0; n < NF; ++n) {
      bf[0][n] = *(const short8*)&Bs[0][wc * (BN / 2) + n * 16 + lr][lk * 8];
      bf[1][n] = *(const short8*)&Bs[1][wc * (BN / 2) + n * 16 + lr][lk * 8];
    }
#pragma unroll
    for (int m = 0; m < MF; ++m)
#pragma unroll
      for (int n = 0; n < NF; ++n) {
        acc[m][n] = __builtin_amdgcn_mfma_f32_16x16x32_bf16(af[0][m], bf[0][n], acc[m][n], 0, 0, 0);
        acc[m][n] = __builtin_amdgcn_mfma_f32_16x16x32_bf16(af[0][m], bf[1][n], acc[m][n], 0, 0, 0);
        acc[m][n] = __builtin_amdgcn_mfma_f32_16x16x32_bf16(af[1][m], bf[0][n], acc[m][n], 0, 0, 0);
      }
    __syncthreads();
  }

#pragma unroll
  for (int m = 0; m < MF; ++m) {
    int row0 = bm * BM + wr * (BM / 2) + m * 16 + lk * 4;
#pragma unroll
    for (int i = 0; i < 4; ++i) {
      int row = row0 + i;
      if (row < M) {
#pragma unroll
        for (int n = 0; n < NF; ++n) {
          int col = bn * BN + wc * (BN / 2) + n * 16 + lr;
          float vv = acc[m][n][i];
          if (bias) vv += bias[col];
          C[(size_t)row * ldc + col] = vv;
        }
      }
    }
  }
}

// ---------------------------------------------------------------------------
// K1 body: head-mean + row-normalize fold (one wave per (l,b,i) row).
// Layers 0..10: all 197 rows. Layer 11: row 0 only (the chain uses only
// e0^T A[11], and row 0's normalizer needs only row 0's own sum).
// ---------------------------------------------------------------------------
__device__ __forceinline__ void k1_body(int rowblk,
                                        const float* __restrict__ attn,
                                        float* __restrict__ P,
                                        float* __restrict__ dvec) {
  int wid = threadIdx.x >> 6;
  int t   = threadIdx.x & 63;
  int row_id = rowblk * 4 + wid;
  int l, b, i;
  if (row_id < K1_FULL_ROWS) {
    l = row_id / 6304;                   // 6304 = 32*197
    int rem = row_id - l * 6304;
    b = rem / 197;
    i = rem - b * 197;
  } else {
    l = 11; b = row_id - K1_FULL_ROWS; i = 0;
  }
  int lb   = l * B_ + b;
  int prow = lb * N1_ + i;
  const float* base = attn + (size_t)lb * (H_ * N1_ * N1_) + (size_t)i * N1_;
  float c0 = 0.f, c1 = 0.f, c2 = 0.f, c3 = 0.f;
#pragma unroll
  for (int h = 0; h < H_; ++h) {
    const float* p = base + (size_t)h * (N1_ * N1_);
    c0 += p[t];
    c1 += p[t + 64];
    c2 += p[t + 128];
    c3 += (t < 5) ? p[t + 192] : 0.f;
  }
  float rs = c0 + c1 + c2 + c3;
#pragma unroll
  for (int o = 32; o; o >>= 1) rs += __shfl_xor(rs, o);
  float inv = 1.f / (rs + 12.f);
  float* Pr = P + (size_t)prow * N1_;
  Pr[t]       = c0 * inv;
  Pr[t + 64]  = c1 * inv;
  Pr[t + 128] = c2 * inv;
  if (t < 5) Pr[t + 192] = c3 * inv;
  if (t == 0) dvec[prow] = 12.f * inv;
}

// ---------------------------------------------------------------------------
// MEGA kernel: every 20th block (900 total) = one 128x128 tile of the fused
// QKV projection GEMM  qkv = x @ [k_w; v_w; q_w]^T  (N=2304, L3-resident
// MFMA compute); all other blocks = k1 head-mean/normalize (HBM stream).
// ---------------------------------------------------------------------------
__global__ __launch_bounds__(256) void mega_k1_qkv(const float* __restrict__ attn,
                                                   float* __restrict__ P,
                                                   float* __restrict__ dvec,
                                                   const float* __restrict__ x,
                                                   const float* __restrict__ k_w,
                                                   const float* __restrict__ v_w,
                                                   const float* __restrict__ q_w,
                                                   float* __restrict__ qkv) {
  int bid = blockIdx.x;
  int g = bid / 20, r = bid % 20;
  if (r == 0 && g < QKV_TILES) {
    int bm = g % 50, bn = g / 50;        // 50 x 18
    gemm_body<128, 128, 4, 4>(bm, bn, x, (const int*)nullptr, k_w, v_w, q_w,
                              (const float*)nullptr, qkv, B_ * N1_, D_, 2304);
  } else {
    int ng = g + (r ? 1 : 0); if (ng > QKV_TILES) ng = QKV_TILES;
    k1_body(bid - ng, attn, P, dvec);
  }
}

// ---------------------------------------------------------------------------
// Standalone GEMM kernel (proj).
// ---------------------------------------------------------------------------
template <int BM, int BN, int MF, int NF>
__global__ __launch_bounds__(256) void gemm_f32in(const float* __restrict__ A,
                                                  const int* __restrict__ gidx,
                                                  const float* __restrict__ W0,
                                                  const float* __restrict__ bias,
                                                  float* __restrict__ C,
                                                  int M, int K, int ldc) {
  gemm_body<BM, BN, MF, NF>(blockIdx.x, blockIdx.y, A, gidx, W0, W0, W0,
                            bias, C, M, K, ldc);
}

// ---------------------------------------------------------------------------
// K2: per-batch rollout chain (row 0 only) + top-k. 1024 threads, 4-way i
// split to shorten the L3-latency-bound inner chain of this 32-block kernel.
// ---------------------------------------------------------------------------
__global__ __launch_bounds__(1024) void k2_chain_topk(const float* __restrict__ P,
                                                      const float* __restrict__ dvec,
                                                      int* __restrict__ gidx) {
  int b = blockIdx.x;
  __shared__ float v[N1_];
  __shared__ float part[4][N1_];
  int t    = threadIdx.x;        // 0..1023
  int quar = t >> 8;             // 0..3
  int j    = t & 255;            // column this thread owns (if <197)

  if (t < N1_) {
    const float* Pr = P + ((size_t)(11 * B_ + b) * N1_) * N1_;   // layer 11, row 0
    v[t] = Pr[t] + (t == 0 ? dvec[(11 * B_ + b) * N1_] : 0.f);
  }
  __syncthreads();

  for (int l = 10; l >= 0; --l) {
    if (j < N1_) {
      const float* Pc = P + ((size_t)(l * B_ + b) * N1_) * N1_ + j;
      float a[8] = {0.f, 0.f, 0.f, 0.f, 0.f, 0.f, 0.f, 0.f};
      int ibeg = (quar * N1_) / 4;
      int iend = ((quar + 1) * N1_) / 4;
      int i = ibeg;
      for (; i + 8 <= iend; i += 8) {
#pragma unroll
        for (int u = 0; u < 8; ++u)
          a[u] += v[i + u] * Pc[(size_t)(i + u) * N1_];
      }
      for (; i < iend; ++i) a[0] += v[i] * Pc[(size_t)i * N1_];
      float s = ((a[0] + a[1]) + (a[2] + a[3])) + ((a[4] + a[5]) + (a[6] + a[7]));
      if (quar == 0) s += v[j] * dvec[(l * B_ + b) * N1_ + j];   // diagonal once
      part[quar][j] = s;
    }
    __syncthreads();
    if (t < N1_) v[t] = (part[0][t] + part[1][t]) + (part[2][t] + part[3][t]);
    __syncthreads();
  }

  // top-k over cls = v[1..196]; jax tie-break: value desc, index asc
  if (t < 64) {
    float val[4];
    int   idx[4];
#pragma unroll
    for (int c = 0; c < 4; ++c) {
      int n = t + c * 64;
      bool ok = (n < N1_ - 1);
      val[c] = ok ? v[n + 1] : -1e30f;
      idx[c] = ok ? n : (1 << 20);
    }
    for (int r = 0; r < R_; ++r) {
      float bv = val[0];
      int   bi = idx[0];
#pragma unroll
      for (int c = 1; c < 4; ++c)
        if (val[c] > bv || (val[c] == bv && idx[c] < bi)) { bv = val[c]; bi = idx[c]; }
#pragma unroll
      for (int o = 32; o; o >>= 1) {
        float ov = __shfl_xor(bv, o);
        int   oi = __shfl_xor(bi, o);
        if (ov > bv || (ov == bv && oi < bi)) { bv = ov; bi = oi; }
      }
      if (t == 0) gidx[b * R_ + r] = b * N1_ + bi + 1;
#pragma unroll
      for (int c = 0; c < 4; ++c)
        if (idx[c] == bi) val[c] = -1e30f;
    }
  }
}

// ---------------------------------------------------------------------------
// K5: per-(b,h) attention (f32). K/V/Q all read from the 2304-wide qkv buf;
// q rows gathered via gidx (projection commutes with the gather).
// ---------------------------------------------------------------------------
__global__ __launch_bounds__(256) void k5_attn(const float* __restrict__ qkv,
                                               const int* __restrict__ gidx,
                                               float* __restrict__ ctx) {
  int bh = blockIdx.x;
  int b = bh / H_, h = bh % H_;
  __shared__ float ks[N1_][68];
  __shared__ float qs[R_][64];
  __shared__ float sc[R_][200];
  __shared__ float rsum[R_];
  int t = threadIdx.x;
  int lane = t & 63, wid = t >> 6;

  const float* kbase = qkv + (size_t)(b * N1_) * 2304 + h * 64;
  for (int n = wid; n < N1_; n += 4)
    ks[n][lane] = kbase[(size_t)n * 2304 + lane];
  for (int e = t; e < R_ * 64; e += 256) {
    int r = e >> 6, d = e & 63;
    int grow = gidx[b * R_ + r];
    qs[r][d] = qkv[(size_t)grow * 2304 + 1536 + h * 64 + d];
  }
  __syncthreads();

  if (t < N1_) {
    float accr[R_];
#pragma unroll
    for (int r = 0; r < R_; ++r) accr[r] = 0.f;
#pragma unroll
    for (int d0 = 0; d0 < 4; ++d0) {
      float4 k0 = *(const float4*)&ks[t][d0 * 16 + 0];
      float4 k1 = *(const float4*)&ks[t][d0 * 16 + 4];
      float4 k2 = *(const float4*)&ks[t][d0 * 16 + 8];
      float4 k3 = *(const float4*)&ks[t][d0 * 16 + 12];
#pragma unroll
      for (int r = 0; r < R_; ++r) {
        float4 q0 = *(const float4*)&qs[r][d0 * 16 + 0];
        float4 q1 = *(const float4*)&qs[r][d0 * 16 + 4];
        float4 q2 = *(const float4*)&qs[r][d0 * 16 + 8];
        float4 q3 = *(const float4*)&qs[r][d0 * 16 + 12];
        accr[r] += k0.x * q0.x + k0.y * q0.y + k0.z * q0.z + k0.w * q0.w
                 + k1.x * q1.x + k1.y * q1.y + k1.z * q1.z + k1.w * q1.w
                 + k2.x * q2.x + k2.y * q2.y + k2.z * q2.z + k2.w * q2.w
                 + k3.x * q3.x + k3.y * q3.y + k3.z * q3.z + k3.w * q3.w;
      }
    }
#pragma unroll
    for (int r = 0; r < R_; ++r) sc[r][t] = accr[r] * 0.125f;
  }
  __syncthreads();

  for (int r = wid; r < R_; r += 4) {
    float x0 = sc[r][lane];
    float x1 = sc[r][lane + 64];
    float x2 = sc[r][lane + 128];
    bool ok3 = (lane + 192 < N1_);
    float x3 = ok3 ? sc[r][lane + 192] : -1e30f;
    float m = fmaxf(fmaxf(x0, x1), fmaxf(x2, x3));
#pragma unroll
    for (int o = 32; o; o >>= 1) m = fmaxf(m, __shfl_xor(m, o));
    float e0 = expf(x0 - m), e1 = expf(x1 - m), e2 = expf(x2 - m);
    float e3 = ok3 ? expf(x3 - m) : 0.f;
    float s = e0 + e1 + e2 + e3;
#pragma unroll
    for (int o = 32; o; o >>= 1) s += __shfl_xor(s, o);
    sc[r][lane] = e0; sc[r][lane + 64] = e1; sc[r][lane + 128] = e2;
    if (ok3) sc[r][lane + 192] = e3;
    if (lane == 0) rsum[r] = s;
  }
  __syncthreads();

  const float* vb = qkv + (size_t)(b * N1_) * 2304 + 768 + h * 64 + lane;
  int r0 = wid, r1 = wid + 4, r2 = wid + 8, r3 = wid + 12, r4 = wid + 16;
  bool has4 = (r4 < R_);
  float a0 = 0.f, a1 = 0.f, a2 = 0.f, a3 = 0.f, a4 = 0.f;
  for (int n = 0; n < N1_; ++n) {
    float vv = vb[(size_t)n * 2304];
    a0 += sc[r0][n] * vv;
    a1 += sc[r1][n] * vv;
    a2 += sc[r2][n] * vv;
    a3 += sc[r3][n] * vv;
    if (has4) a4 += sc[r4][n] * vv;
  }
  float* cb = ctx + (size_t)(b * R_) * D_ + h * 64 + lane;
  cb[(size_t)r0 * D_] = a0 / rsum[r0];
  cb[(size_t)r1 * D_] = a1 / rsum[r1];
  cb[(size_t)r2 * D_] = a2 / rsum[r2];
  cb[(size_t)r3 * D_] = a3 / rsum[r3];
  if (has4) cb[(size_t)r4 * D_] = a4 / rsum[r4];
}

// ---------------------------------------------------------------------------
extern "C" void kernel_launch(void* const* d_in, const int* in_sizes, int n_in,
                              void* d_out, int out_size, void* d_ws, size_t ws_size,
                              hipStream_t stream) {
  const float* x      = (const float*)d_in[0];
  const float* attn   = (const float*)d_in[1];
  const float* q_w    = (const float*)d_in[2];
  const float* k_w    = (const float*)d_in[3];
  const float* v_w    = (const float*)d_in[4];
  const float* proj_w = (const float*)d_in[5];
  const float* proj_b = (const float*)d_in[6];
  float* out = (float*)d_out;

  // workspace layout (256B aligned segments)
  char* w = (char*)d_ws;
  auto take = [&](size_t bytes) { char* p = w; w += (bytes + 255) & ~(size_t)255; return p; };
  float* P    = (float*)take((size_t)L_ * B_ * N1_ * N1_ * 4);   // 59.6 MB
  float* dvec = (float*)take((size_t)L_ * B_ * N1_ * 4);
  int*   gidx = (int*)take(B_ * R_ * 4);
  float* qkv  = (float*)take((size_t)B_ * N1_ * 2304 * 4);       // 58.1 MB
  float* ctx  = (float*)take((size_t)B_ * R_ * D_ * 4);

  // 1) MEGA: k1 head-mean/normalize (HBM stream, ~656MB) overlapped with the
  //    full QKV projection GEMM (L3-resident MFMA compute) in one launch.
  hipLaunchKernelGGL(mega_k1_qkv, dim3(MEGA_BLOCKS), dim3(256), 0, stream,
                     attn, P, dvec, x, k_w, v_w, q_w, qkv);
  // 2) rollout chain (row 0) + top-19 indices
  hipLaunchKernelGGL(k2_chain_topk, dim3(B_), dim3(1024), 0, stream, P, dvec, gidx);
  // 3) attention per (b,h), q gathered from qkv
  hipLaunchKernelGGL(k5_attn, dim3(B_ * H_), dim3(256), 0, stream, qkv, gidx, ctx);
  // 4) output projection + bias -> d_out
  hipLaunchKernelGGL((gemm_f32in<64, 64, 2, 2>), dim3(10, 12), dim3(256), 0, stream,
                     ctx, (const int*)nullptr, proj_w, proj_b, out, B_ * R_, D_, D_);
}

// Round 5
// 401.466 us; speedup vs baseline: 1.2924x; 1.2924x over previous
//
#include <hip/hip_runtime.h>
#include <math.h>

#define L_  12
#define B_  32
#define H_  12
#define N1_ 197
#define D_  768
#define R_  19
#define M_TOK (B_ * N1_)               // 6304

#define K1_FULL_ROWS  69344            // 11 layers * 32 b * 197 rows
#define K1_ROWS       69376            // + 32 layer-11 row-0 rows
#define K1_BLOCKS     (K1_ROWS / 4)    // 17344

typedef __attribute__((ext_vector_type(8))) short short8;
typedef __attribute__((ext_vector_type(4))) float f32x4;

// ---------------------------------------------------------------------------
// f32 -> bf16 hi/lo split. hi = rn(f), lo = rn(f - hi).
// hh + hl + lh reproduces the f32 product to ~2^-17 relative.
// ---------------------------------------------------------------------------
__device__ inline ushort f2bf_rn(float f) {
  unsigned u = __float_as_uint(f);
  unsigned r = (u + 0x7FFFu + ((u >> 16) & 1u)) >> 16;
  return (ushort)r;
}
__device__ inline float bf2f(ushort h) { return __uint_as_float((unsigned)h << 16); }
__device__ inline void cvt4(float4 f, ushort4& h, ushort4& l) {
  h.x = f2bf_rn(f.x); l.x = f2bf_rn(f.x - bf2f(h.x));
  h.y = f2bf_rn(f.y); l.y = f2bf_rn(f.y - bf2f(h.y));
  h.z = f2bf_rn(f.z); l.z = f2bf_rn(f.z - bf2f(h.z));
  h.w = f2bf_rn(f.w); l.w = f2bf_rn(f.w - bf2f(h.w));
}

typedef const __attribute__((address_space(1))) void* as1_vp;
typedef __attribute__((address_space(3))) void* as3_vp;
__device__ __forceinline__ void gl_lds16(const void* g, void* s) {
  __builtin_amdgcn_global_load_lds((as1_vp)g, (as3_vp)s, 16, 0, 0);
}

// ---------------------------------------------------------------------------
// PACK: f32 [row][768] -> u16 [row][24][ hi(32) | lo(32) ]  (128B per (row,kb))
// Thread = one (row, kb). Fully coalesced 128B read + 128B write.
// Row source: row < split ? s0[row] : s1[row-split].
// ---------------------------------------------------------------------------
__global__ __launch_bounds__(256) void pack2(const float* __restrict__ s0,
                                             const float* __restrict__ s1,
                                             int split_row, int total_rows,
                                             ushort* __restrict__ dst) {
  int t = blockIdx.x * 256 + threadIdx.x;
  if (t >= total_rows * 24) return;
  int row = t / 24, kb = t - row * 24;
  const float* src = ((row < split_row) ? (s0 + (size_t)row * D_)
                                        : (s1 + (size_t)(row - split_row) * D_)) + kb * 32;
  ushort* d = dst + (size_t)t * 64;
#pragma unroll
  for (int u = 0; u < 8; ++u) {
    float4 f = *(const float4*)(src + u * 4);
    ushort4 h, l; cvt4(f, h, l);
    *(ushort4*)(d + u * 4)      = h;
    *(ushort4*)(d + 32 + u * 4) = l;
  }
}

// ---------------------------------------------------------------------------
// FAST split-bf16 GEMM (KV projection): C[m,n] = sum_k x[m,k]*w[n,k]
// from packed hi/lo buffers. 128x128 tile, BK=32, 4 waves (2x2), each wave
// 64x64 via 4x4 16x16x32 fragments, 3 MFMA per fragment pair (hh+hl+lh).
// Staging: global_load_lds width=16, LINEAR LDS dest; swizzle achieved by
// pre-swizzling the per-lane GLOBAL source chunk: c = c' ^ (row&7)  [m173].
// Fragment ds_read_b128 at chunk c' = c ^ (row&7) -> uniform bank tiling
// (unswizzled would be 8-way conflicted at the 128B row stride).
// ---------------------------------------------------------------------------
__global__ __launch_bounds__(256) void gemm_kv_fast(const ushort* __restrict__ xpack,
                                                    const ushort* __restrict__ wpack,
                                                    float* __restrict__ C) {
  __shared__ __attribute__((aligned(16))) ushort As[128 * 64];
  __shared__ __attribute__((aligned(16))) ushort Bs[128 * 64];
  int tid = threadIdx.x, lane = tid & 63, wid = tid >> 6;
  int wr = wid >> 1, wc = wid & 1;
  int lr = lane & 15, lk = lane >> 4;
  int bm = blockIdx.x, bn = blockIdx.y;      // 50 x 12

  // staging: wave w stages rows [w*32, w*32+32) of both tiles, 4 insts of
  // 8 rows (64 chunks of 16B) each. Lane l -> row +l/8, LDS chunk c'=l&7,
  // global chunk c = c' ^ (row&7).
  const ushort* asrc[4];
  const ushort* bsrc[4];
  ushort* adst[4];
  ushort* bdst[4];
  int lrow = lane >> 3, cpr = lane & 7;
#pragma unroll
  for (int i = 0; i < 4; ++i) {
    int r_loc = wid * 32 + i * 8 + lrow;
    int c     = cpr ^ (r_loc & 7);
    int ga    = bm * 128 + r_loc; if (ga >= M_TOK) ga = M_TOK - 1;
    int gb    = bn * 128 + r_loc;              // N=1536 exact
    asrc[i] = xpack + (size_t)ga * (24 * 64) + c * 8;
    bsrc[i] = wpack + (size_t)gb * (24 * 64) + c * 8;
    adst[i] = &As[(wid * 32 + i * 8) * 64];
    bdst[i] = &Bs[(wid * 32 + i * 8) * 64];
  }

  // fragment chunk offsets (ushort units). A/B row R: R&7 == lr&7.
  int oh = (lk ^ (lr & 7)) * 8;      // hi chunk c'=lk^(R&7)
  int ol = oh ^ 32;                  // lo chunk (c xor 4 -> +-32 ushorts)

  f32x4 acc[4][4] = {};

#pragma unroll
  for (int i = 0; i < 4; ++i) { gl_lds16(asrc[i], adst[i]); gl_lds16(bsrc[i], bdst[i]); }

  for (int kb = 0; kb < 24; ++kb) {
    __syncthreads();                 // drains vmcnt -> tile kb ready
    short8 afh[4], afl[4], bfh[4], bfl[4];
#pragma unroll
    for (int m = 0; m < 4; ++m) {
      const ushort* rp = &As[(wr * 64 + m * 16 + lr) * 64];
      afh[m] = *(const short8*)(rp + oh);
      afl[m] = *(const short8*)(rp + ol);
    }
#pragma unroll
    for (int n = 0; n < 4; ++n) {
      const ushort* rp = &Bs[(wc * 64 + n * 16 + lr) * 64];
      bfh[n] = *(const short8*)(rp + oh);
      bfl[n] = *(const short8*)(rp + ol);
    }
    __syncthreads();                 // all waves done reading LDS
    if (kb < 23) {                   // issue next tile; flies under the MFMAs
#pragma unroll
      for (int i = 0; i < 4; ++i) {
        gl_lds16(asrc[i] + (kb + 1) * 64, adst[i]);
        gl_lds16(bsrc[i] + (kb + 1) * 64, bdst[i]);
      }
    }
#pragma unroll
    for (int m = 0; m < 4; ++m)
#pragma unroll
      for (int n = 0; n < 4; ++n) {
        acc[m][n] = __builtin_amdgcn_mfma_f32_16x16x32_bf16(afh[m], bfh[n], acc[m][n], 0, 0, 0);
        acc[m][n] = __builtin_amdgcn_mfma_f32_16x16x32_bf16(afh[m], bfl[n], acc[m][n], 0, 0, 0);
        acc[m][n] = __builtin_amdgcn_mfma_f32_16x16x32_bf16(afl[m], bfh[n], acc[m][n], 0, 0, 0);
      }
  }

#pragma unroll
  for (int m = 0; m < 4; ++m) {
    int row0 = bm * 128 + wr * 64 + m * 16 + (lane >> 4) * 4;
#pragma unroll
    for (int i = 0; i < 4; ++i) {
      int row = row0 + i;
      if (row < M_TOK) {
#pragma unroll
        for (int n = 0; n < 4; ++n) {
          int col = bn * 128 + wc * 64 + n * 16 + lr;
          C[(size_t)row * 1536 + col] = acc[m][n][i];
        }
      }
    }
  }
}

// ---------------------------------------------------------------------------
// K1: head-mean + row-normalize fold, standalone (no LDS -> high occupancy).
// Layers 0..10 all rows; layer 11 row 0 only.
// ---------------------------------------------------------------------------
__global__ __launch_bounds__(256) void k1_mean_norm(const float* __restrict__ attn,
                                                    float* __restrict__ P,
                                                    float* __restrict__ dvec) {
  int wid = threadIdx.x >> 6;
  int t   = threadIdx.x & 63;
  int row_id = blockIdx.x * 4 + wid;
  int l, b, i;
  if (row_id < K1_FULL_ROWS) {
    l = row_id / 6304;
    int rem = row_id - l * 6304;
    b = rem / 197;
    i = rem - b * 197;
  } else {
    l = 11; b = row_id - K1_FULL_ROWS; i = 0;
  }
  int lb   = l * B_ + b;
  int prow = lb * N1_ + i;
  const float* base = attn + (size_t)lb * (H_ * N1_ * N1_) + (size_t)i * N1_;
  float c0 = 0.f, c1 = 0.f, c2 = 0.f, c3 = 0.f;
#pragma unroll
  for (int h = 0; h < H_; ++h) {
    const float* p = base + (size_t)h * (N1_ * N1_);
    c0 += p[t];
    c1 += p[t + 64];
    c2 += p[t + 128];
    c3 += (t < 5) ? p[t + 192] : 0.f;
  }
  float rs = c0 + c1 + c2 + c3;
#pragma unroll
  for (int o = 32; o; o >>= 1) rs += __shfl_xor(rs, o);
  float inv = 1.f / (rs + 12.f);
  float* Pr = P + (size_t)prow * N1_;
  Pr[t]       = c0 * inv;
  Pr[t + 64]  = c1 * inv;
  Pr[t + 128] = c2 * inv;
  if (t < 5) Pr[t + 192] = c3 * inv;
  if (t == 0) dvec[prow] = 12.f * inv;
}

// ---------------------------------------------------------------------------
// K2: per-batch rollout chain (row 0 only) + top-k. 1024 threads, 4-way i.
// ---------------------------------------------------------------------------
__global__ __launch_bounds__(1024) void k2_chain_topk(const float* __restrict__ P,
                                                      const float* __restrict__ dvec,
                                                      int* __restrict__ gidx) {
  int b = blockIdx.x;
  __shared__ float v[N1_];
  __shared__ float part[4][N1_];
  int t = threadIdx.x, quar = t >> 8, j = t & 255;

  if (t < N1_) {
    const float* Pr = P + ((size_t)(11 * B_ + b) * N1_) * N1_;
    v[t] = Pr[t] + (t == 0 ? dvec[(11 * B_ + b) * N1_] : 0.f);
  }
  __syncthreads();

  for (int l = 10; l >= 0; --l) {
    if (j < N1_) {
      const float* Pc = P + ((size_t)(l * B_ + b) * N1_) * N1_ + j;
      float a[8] = {0.f, 0.f, 0.f, 0.f, 0.f, 0.f, 0.f, 0.f};
      int ibeg = (quar * N1_) / 4;
      int iend = ((quar + 1) * N1_) / 4;
      int i = ibeg;
      for (; i + 8 <= iend; i += 8) {
#pragma unroll
        for (int u = 0; u < 8; ++u)
          a[u] += v[i + u] * Pc[(size_t)(i + u) * N1_];
      }
      for (; i < iend; ++i) a[0] += v[i] * Pc[(size_t)i * N1_];
      float s = ((a[0] + a[1]) + (a[2] + a[3])) + ((a[4] + a[5]) + (a[6] + a[7]));
      if (quar == 0) s += v[j] * dvec[(l * B_ + b) * N1_ + j];
      part[quar][j] = s;
    }
    __syncthreads();
    if (t < N1_) v[t] = (part[0][t] + part[1][t]) + (part[2][t] + part[3][t]);
    __syncthreads();
  }

  if (t < 64) {
    float val[4];
    int   idx[4];
#pragma unroll
    for (int c = 0; c < 4; ++c) {
      int n = t + c * 64;
      bool ok = (n < N1_ - 1);
      val[c] = ok ? v[n + 1] : -1e30f;
      idx[c] = ok ? n : (1 << 20);
    }
    for (int r = 0; r < R_; ++r) {
      float bv = val[0];
      int   bi = idx[0];
#pragma unroll
      for (int c = 1; c < 4; ++c)
        if (val[c] > bv || (val[c] == bv && idx[c] < bi)) { bv = val[c]; bi = idx[c]; }
#pragma unroll
      for (int o = 32; o; o >>= 1) {
        float ov = __shfl_xor(bv, o);
        int   oi = __shfl_xor(bi, o);
        if (ov > bv || (ov == bv && oi < bi)) { bv = ov; bi = oi; }
      }
      if (t == 0) gidx[b * R_ + r] = b * N1_ + bi + 1;
#pragma unroll
      for (int c = 0; c < 4; ++c)
        if (idx[c] == bi) val[c] = -1e30f;
    }
  }
}

// ---------------------------------------------------------------------------
// Slow (reg-staging) split-bf16 GEMM for the tiny q / proj matmuls.
// ---------------------------------------------------------------------------
#define PK 40
template <int BM, int BN, int MF, int NF>
__device__ __forceinline__ void gemm_body(int bm, int bn,
                                          const float* __restrict__ A,
                                          const int* __restrict__ gidx,
                                          const float* __restrict__ W0,
                                          const float* __restrict__ bias,
                                          float* __restrict__ C,
                                          int M, int K, int ldc) {
  __shared__ __attribute__((aligned(16))) ushort As[2][BM][PK];
  __shared__ __attribute__((aligned(16))) ushort Bs[2][BN][PK];
  constexpr int TPRA = 256 / BM;
  constexpr int EPTA = 32 / TPRA;
  constexpr int NA4  = EPTA / 4;
  constexpr int TPRB = 256 / BN;
  constexpr int EPTB = 32 / TPRB;
  constexpr int NB4  = EPTB / 4;

  int tid  = threadIdx.x;
  int lane = tid & 63, wid = tid >> 6;
  int wr = wid >> 1, wc = wid & 1;
  int lr = lane & 15, lk = lane >> 4;

  int arow_s = tid / TPRA;
  int akoff  = (tid % TPRA) * EPTA;
  int ar = bm * BM + arow_s; if (ar >= M) ar = M - 1;
  int asrc = gidx ? gidx[ar] : ar;
  const float* ap = A + (size_t)asrc * K + akoff;

  int brow_s = tid / TPRB;
  int bkoff  = (tid % TPRB) * EPTB;
  int wrow   = bn * BN + brow_s;
  const float* wp = W0 + (size_t)wrow * K + bkoff;

  f32x4 acc[MF][NF] = {};

  float4 pa[NA4], pb[NB4];
#pragma unroll
  for (int u = 0; u < NA4; ++u) pa[u] = *(const float4*)(ap + u * 4);
#pragma unroll
  for (int u = 0; u < NB4; ++u) pb[u] = *(const float4*)(wp + u * 4);

  for (int k0 = 0; k0 < K; k0 += 32) {
#pragma unroll
    for (int u = 0; u < NA4; ++u) {
      ushort4 h, l; cvt4(pa[u], h, l);
      *(ushort4*)&As[0][arow_s][akoff + u * 4] = h;
      *(ushort4*)&As[1][arow_s][akoff + u * 4] = l;
    }
#pragma unroll
    for (int u = 0; u < NB4; ++u) {
      ushort4 h, l; cvt4(pb[u], h, l);
      *(ushort4*)&Bs[0][brow_s][bkoff + u * 4] = h;
      *(ushort4*)&Bs[1][brow_s][bkoff + u * 4] = l;
    }
    __syncthreads();

    int kn = k0 + 32;
    if (kn < K) {
#pragma unroll
      for (int u = 0; u < NA4; ++u) pa[u] = *(const float4*)(ap + kn + u * 4);
#pragma unroll
      for (int u = 0; u < NB4; ++u) pb[u] = *(const float4*)(wp + kn + u * 4);
    }

    short8 af[2][MF], bf[2][NF];
#pragma unroll
    for (int m = 0; m < MF; ++m) {
      af[0][m] = *(const short8*)&As[0][wr * (BM / 2) + m * 16 + lr][lk * 8];
      af[1][m] = *(const short8*)&As[1][wr * (BM / 2) + m * 16 + lr][lk * 8];
    }
#pragma unroll
    for (int n = 0; n < NF; ++n) {
      bf[0][n] = *(const short8*)&Bs[0][wc * (BN / 2) + n * 16 + lr][lk * 8];
      bf[1][n] = *(const short8*)&Bs[1][wc * (BN / 2) + n * 16 + lr][lk * 8];
    }
#pragma unroll
    for (int m = 0; m < MF; ++m)
#pragma unroll
      for (int n = 0; n < NF; ++n) {
        acc[m][n] = __builtin_amdgcn_mfma_f32_16x16x32_bf16(af[0][m], bf[0][n], acc[m][n], 0, 0, 0);
        acc[m][n] = __builtin_amdgcn_mfma_f32_16x16x32_bf16(af[0][m], bf[1][n], acc[m][n], 0, 0, 0);
        acc[m][n] = __builtin_amdgcn_mfma_f32_16x16x32_bf16(af[1][m], bf[0][n], acc[m][n], 0, 0, 0);
      }
    __syncthreads();
  }

#pragma unroll
  for (int m = 0; m < MF; ++m) {
    int row0 = bm * BM + wr * (BM / 2) + m * 16 + lk * 4;
#pragma unroll
    for (int i = 0; i < 4; ++i) {
      int row = row0 + i;
      if (row < M) {
#pragma unroll
        for (int n = 0; n < NF; ++n) {
          int col = bn * BN + wc * (BN / 2) + n * 16 + lr;
          float vv = acc[m][n][i];
          if (bias) vv += bias[col];
          C[(size_t)row * ldc + col] = vv;
        }
      }
    }
  }
}

template <int BM, int BN, int MF, int NF>
__global__ __launch_bounds__(256) void gemm_f32in(const float* __restrict__ A,
                                                  const int* __restrict__ gidx,
                                                  const float* __restrict__ W0,
                                                  const float* __restrict__ bias,
                                                  float* __restrict__ C,
                                                  int M, int K, int ldc) {
  gemm_body<BM, BN, MF, NF>(blockIdx.x, blockIdx.y, A, gidx, W0, bias, C, M, K, ldc);
}

// ---------------------------------------------------------------------------
// K5: per-(b,h) attention (f32).
// ---------------------------------------------------------------------------
__global__ __launch_bounds__(256) void k5_attn(const float* __restrict__ kvb,
                                               const float* __restrict__ qb,
                                               float* __restrict__ ctx) {
  int bh = blockIdx.x;
  int b = bh / H_, h = bh % H_;
  __shared__ float ks[N1_][68];
  __shared__ float qs[R_][64];
  __shared__ float sc[R_][200];
  __shared__ float rsum[R_];
  int t = threadIdx.x;
  int lane = t & 63, wid = t >> 6;

  const float* kbase = kvb + (size_t)b * N1_ * 1536 + h * 64;
  for (int n = wid; n < N1_; n += 4)
    ks[n][lane] = kbase[(size_t)n * 1536 + lane];
  const float* qrow = qb + (size_t)b * R_ * D_ + h * 64;
  for (int e = t; e < R_ * 64; e += 256) {
    int r = e >> 6, d = e & 63;
    qs[r][d] = qrow[(size_t)r * D_ + d];
  }
  __syncthreads();

  if (t < N1_) {
    float accr[R_];
#pragma unroll
    for (int r = 0; r < R_; ++r) accr[r] = 0.f;
#pragma unroll
    for (int d0 = 0; d0 < 4; ++d0) {
      float4 k0 = *(const float4*)&ks[t][d0 * 16 + 0];
      float4 k1 = *(const float4*)&ks[t][d0 * 16 + 4];
      float4 k2 = *(const float4*)&ks[t][d0 * 16 + 8];
      float4 k3 = *(const float4*)&ks[t][d0 * 16 + 12];
#pragma unroll
      for (int r = 0; r < R_; ++r) {
        float4 q0 = *(const float4*)&qs[r][d0 * 16 + 0];
        float4 q1 = *(const float4*)&qs[r][d0 * 16 + 4];
        float4 q2 = *(const float4*)&qs[r][d0 * 16 + 8];
        float4 q3 = *(const float4*)&qs[r][d0 * 16 + 12];
        accr[r] += k0.x * q0.x + k0.y * q0.y + k0.z * q0.z + k0.w * q0.w
                 + k1.x * q1.x + k1.y * q1.y + k1.z * q1.z + k1.w * q1.w
                 + k2.x * q2.x + k2.y * q2.y + k2.z * q2.z + k2.w * q2.w
                 + k3.x * q3.x + k3.y * q3.y + k3.z * q3.z + k3.w * q3.w;
      }
    }
#pragma unroll
    for (int r = 0; r < R_; ++r) sc[r][t] = accr[r] * 0.125f;
  }
  __syncthreads();

  for (int r = wid; r < R_; r += 4) {
    float x0 = sc[r][lane];
    float x1 = sc[r][lane + 64];
    float x2 = sc[r][lane + 128];
    bool ok3 = (lane + 192 < N1_);
    float x3 = ok3 ? sc[r][lane + 192] : -1e30f;
    float m = fmaxf(fmaxf(x0, x1), fmaxf(x2, x3));
#pragma unroll
    for (int o = 32; o; o >>= 1) m = fmaxf(m, __shfl_xor(m, o));
    float e0 = expf(x0 - m), e1 = expf(x1 - m), e2 = expf(x2 - m);
    float e3 = ok3 ? expf(x3 - m) : 0.f;
    float s = e0 + e1 + e2 + e3;
#pragma unroll
    for (int o = 32; o; o >>= 1) s += __shfl_xor(s, o);
    sc[r][lane] = e0; sc[r][lane + 64] = e1; sc[r][lane + 128] = e2;
    if (ok3) sc[r][lane + 192] = e3;
    if (lane == 0) rsum[r] = s;
  }
  __syncthreads();

  const float* vb = kvb + (size_t)b * N1_ * 1536 + 768 + h * 64 + lane;
  int r0 = wid, r1 = wid + 4, r2 = wid + 8, r3 = wid + 12, r4 = wid + 16;
  bool has4 = (r4 < R_);
  float a0 = 0.f, a1 = 0.f, a2 = 0.f, a3 = 0.f, a4 = 0.f;
  for (int n = 0; n < N1_; ++n) {
    float vv = vb[(size_t)n * 1536];
    a0 += sc[r0][n] * vv;
    a1 += sc[r1][n] * vv;
    a2 += sc[r2][n] * vv;
    a3 += sc[r3][n] * vv;
    if (has4) a4 += sc[r4][n] * vv;
  }
  float* cb = ctx + (size_t)(b * R_) * D_ + h * 64 + lane;
  cb[(size_t)r0 * D_] = a0 / rsum[r0];
  cb[(size_t)r1 * D_] = a1 / rsum[r1];
  cb[(size_t)r2 * D_] = a2 / rsum[r2];
  cb[(size_t)r3 * D_] = a3 / rsum[r3];
  if (has4) cb[(size_t)r4 * D_] = a4 / rsum[r4];
}

// ---------------------------------------------------------------------------
extern "C" void kernel_launch(void* const* d_in, const int* in_sizes, int n_in,
                              void* d_out, int out_size, void* d_ws, size_t ws_size,
                              hipStream_t stream) {
  const float* x      = (const float*)d_in[0];
  const float* attn   = (const float*)d_in[1];
  const float* q_w    = (const float*)d_in[2];
  const float* k_w    = (const float*)d_in[3];
  const float* v_w    = (const float*)d_in[4];
  const float* proj_w = (const float*)d_in[5];
  const float* proj_b = (const float*)d_in[6];
  float* out = (float*)d_out;

  char* w = (char*)d_ws;
  auto take = [&](size_t bytes) { char* p = w; w += (bytes + 255) & ~(size_t)255; return p; };
  float*  P     = (float*)take((size_t)L_ * B_ * N1_ * N1_ * 4);   // 59.6 MB
  float*  dvec  = (float*)take((size_t)L_ * B_ * N1_ * 4);
  int*    gidx  = (int*)take(B_ * R_ * 4);
  float*  kvb   = (float*)take((size_t)M_TOK * 1536 * 4);          // 38.7 MB
  float*  qbuf  = (float*)take((size_t)B_ * R_ * D_ * 4);
  float*  ctx   = (float*)take((size_t)B_ * R_ * D_ * 4);
  ushort* xpack = (ushort*)take((size_t)M_TOK * 24 * 64 * 2);      // 19.4 MB
  ushort* wpack = (ushort*)take((size_t)1536 * 24 * 64 * 2);       // 4.7 MB

  // 1) pack x and [k_w; v_w] into hi/lo bf16 (128B per (row,kb) block)
  hipLaunchKernelGGL(pack2, dim3((M_TOK * 24 + 255) / 256), dim3(256), 0, stream,
                     x, x, 1 << 30, M_TOK, xpack);
  hipLaunchKernelGGL(pack2, dim3((1536 * 24 + 255) / 256), dim3(256), 0, stream,
                     k_w, v_w, 768, 1536, wpack);
  // 2) K,V projection via fast MFMA GEMM (xpack L2-warm)
  hipLaunchKernelGGL(gemm_kv_fast, dim3(50, 12), dim3(256), 0, stream,
                     xpack, wpack, kvb);
  // 3) head-mean + normalize (HBM stream, standalone -> full occupancy)
  hipLaunchKernelGGL(k1_mean_norm, dim3(K1_BLOCKS), dim3(256), 0, stream,
                     attn, P, dvec);
  // 4) rollout chain (row 0) + top-19 indices
  hipLaunchKernelGGL(k2_chain_topk, dim3(B_), dim3(1024), 0, stream, P, dvec, gidx);
  // 5) q projection of gathered top-R tokens
  hipLaunchKernelGGL((gemm_f32in<64, 64, 2, 2>), dim3(10, 12), dim3(256), 0, stream,
                     x, gidx, q_w, (const float*)nullptr, qbuf, B_ * R_, D_, D_);
  // 6) attention per (b,h)
  hipLaunchKernelGGL(k5_attn, dim3(B_ * H_), dim3(256), 0, stream, kvb, qbuf, ctx);
  // 7) output projection + bias -> d_out
  hipLaunchKernelGGL((gemm_f32in<64, 64, 2, 2>), dim3(10, 12), dim3(256), 0, stream,
                     ctx, (const int*)nullptr, proj_w, proj_b, out, B_ * R_, D_, D_);
}

// Round 6
// 346.221 us; speedup vs baseline: 1.4986x; 1.1596x over previous
//
#include <hip/hip_runtime.h>
#include <math.h>

#define L_  12
#define B_  32
#define H_  12
#define N1_ 197
#define D_  768
#define R_  19
#define M_TOK (B_ * N1_)               // 6304
#define NN (N1_ * N1_)                 // 38809

#define K1_FULL_ROWS  69344            // 11 layers * 32 b * 197 rows
#define K1_ROWS       69376            // + 32 layer-11 row-0 rows
#define K1_BLOCKS     (K1_ROWS / 4)    // 17344
#define PACK_ROWS     (M_TOK + 2304)   // x rows + [k;v;q] weight rows = 8608
#define PACK_BLOCKS   ((PACK_ROWS * 24 + 255) / 256)   // 807

typedef __attribute__((ext_vector_type(8))) short short8;
typedef __attribute__((ext_vector_type(4))) float f32x4;

// unaligned float4 load/store (row bases are only 4B-aligned; gfx950 global
// unaligned dwordx4 is supported — memcpy lowers to one load <4 x float>)
__device__ __forceinline__ f32x4 ld4u(const float* p) {
  f32x4 r; __builtin_memcpy(&r, p, 16); return r;
}
__device__ __forceinline__ void st4u(float* p, f32x4 v) {
  __builtin_memcpy(p, &v, 16);
}

// ---------------------------------------------------------------------------
// f32 -> bf16 hi/lo split. hi = rn(f), lo = rn(f - hi).
// ---------------------------------------------------------------------------
__device__ inline ushort f2bf_rn(float f) {
  unsigned u = __float_as_uint(f);
  unsigned r = (u + 0x7FFFu + ((u >> 16) & 1u)) >> 16;
  return (ushort)r;
}
__device__ inline float bf2f(ushort h) { return __uint_as_float((unsigned)h << 16); }
__device__ inline void cvt4(float4 f, ushort4& h, ushort4& l) {
  h.x = f2bf_rn(f.x); l.x = f2bf_rn(f.x - bf2f(h.x));
  h.y = f2bf_rn(f.y); l.y = f2bf_rn(f.y - bf2f(h.y));
  h.z = f2bf_rn(f.z); l.z = f2bf_rn(f.z - bf2f(h.z));
  h.w = f2bf_rn(f.w); l.w = f2bf_rn(f.w - bf2f(h.w));
}

typedef const __attribute__((address_space(1))) void* as1_vp;
typedef __attribute__((address_space(3))) void* as3_vp;
__device__ __forceinline__ void gl_lds16(const void* g, void* s) {
  __builtin_amdgcn_global_load_lds((as1_vp)g, (as3_vp)s, 16, 0, 0);
}

// ---------------------------------------------------------------------------
// MEGA: blocks [0, K1_BLOCKS) = k1 head-mean+normalize, VECTORIZED:
//   one wave per (l,b,i) row; lane t covers j=4t..4t+3 via unaligned float4.
//   Layers 0..10 all rows; layer 11 row 0 only.
// blocks [K1_BLOCKS, +PACK_BLOCKS) = pack x and [k_w;v_w;q_w] into bf16 hi/lo
//   [row][24][hi(32)|lo(32)] (128B per (row,kb)). Neither path uses LDS ->
//   no resource-union penalty (R4 lesson).
// ---------------------------------------------------------------------------
__global__ __launch_bounds__(256) void mega_k1_pack(const float* __restrict__ attn,
                                                    float* __restrict__ P,
                                                    float* __restrict__ dvec,
                                                    const float* __restrict__ x,
                                                    const float* __restrict__ k_w,
                                                    const float* __restrict__ v_w,
                                                    const float* __restrict__ q_w,
                                                    ushort* __restrict__ xpack,
                                                    ushort* __restrict__ wpack) {
  int bid = blockIdx.x;
  if (bid < K1_BLOCKS) {
    int wid = threadIdx.x >> 6;
    int t   = threadIdx.x & 63;
    int row_id = bid * 4 + wid;
    int l, b, i;
    if (row_id < K1_FULL_ROWS) {
      l = row_id / 6304;
      int rem = row_id - l * 6304;
      b = rem / 197;
      i = rem - b * 197;
    } else {
      l = 11; b = row_id - K1_FULL_ROWS; i = 0;
    }
    int lb   = l * B_ + b;
    int prow = lb * N1_ + i;
    const float* base = attn + (size_t)lb * (H_ * NN) + (size_t)i * N1_;
    f32x4 acc = {0.f, 0.f, 0.f, 0.f};
    if (t < 49) {
      const float* p = base + 4 * t;
#pragma unroll
      for (int h = 0; h < H_; ++h) acc += ld4u(p + (size_t)h * NN);
    } else if (t == 49) {
      const float* p = base + 196;
#pragma unroll
      for (int h = 0; h < H_; ++h) acc.x += p[(size_t)h * NN];
    }
    float s = (acc.x + acc.y) + (acc.z + acc.w);
#pragma unroll
    for (int o = 32; o; o >>= 1) s += __shfl_xor(s, o);
    float inv = 1.f / (s + 12.f);
    float* Pr = P + (size_t)prow * N1_;
    if (t < 49)       st4u(Pr + 4 * t, acc * inv);
    else if (t == 49) Pr[196] = acc.x * inv;
    if (t == 0) dvec[prow] = 12.f * inv;
  } else {
    int t = (bid - K1_BLOCKS) * 256 + threadIdx.x;
    if (t >= PACK_ROWS * 24) return;
    int row = t / 24, kb = t - row * 24;
    const float* src;
    ushort* dst;
    if (row < M_TOK) {
      src = x + (size_t)row * D_;
      dst = xpack + (size_t)row * 1536;
    } else {
      int wr = row - M_TOK;                 // 0..2303
      int g = wr / 768, rl = wr - g * 768;
      const float* wsrc = (g == 0) ? k_w : (g == 1) ? v_w : q_w;
      src = wsrc + (size_t)rl * D_;
      dst = wpack + (size_t)wr * 1536;
    }
    src += kb * 32;
    dst += kb * 64;
#pragma unroll
    for (int u = 0; u < 8; ++u) {
      float4 f = *(const float4*)(src + u * 4);
      ushort4 h, l2; cvt4(f, h, l2);
      *(ushort4*)(dst + u * 4)      = h;
      *(ushort4*)(dst + 32 + u * 4) = l2;
    }
  }
}

// ---------------------------------------------------------------------------
// K2: per-batch rollout chain (row 0 only) + top-k. 1024 threads, 4-way i.
// ---------------------------------------------------------------------------
__global__ __launch_bounds__(1024) void k2_chain_topk(const float* __restrict__ P,
                                                      const float* __restrict__ dvec,
                                                      int* __restrict__ gidx) {
  int b = blockIdx.x;
  __shared__ float v[N1_];
  __shared__ float part[4][N1_];
  int t = threadIdx.x, quar = t >> 8, j = t & 255;

  if (t < N1_) {
    const float* Pr = P + ((size_t)(11 * B_ + b) * N1_) * N1_;
    v[t] = Pr[t] + (t == 0 ? dvec[(11 * B_ + b) * N1_] : 0.f);
  }
  __syncthreads();

  for (int l = 10; l >= 0; --l) {
    if (j < N1_) {
      const float* Pc = P + ((size_t)(l * B_ + b) * N1_) * N1_ + j;
      float a[8] = {0.f, 0.f, 0.f, 0.f, 0.f, 0.f, 0.f, 0.f};
      int ibeg = (quar * N1_) / 4;
      int iend = ((quar + 1) * N1_) / 4;
      int i = ibeg;
      for (; i + 8 <= iend; i += 8) {
#pragma unroll
        for (int u = 0; u < 8; ++u)
          a[u] += v[i + u] * Pc[(size_t)(i + u) * N1_];
      }
      for (; i < iend; ++i) a[0] += v[i] * Pc[(size_t)i * N1_];
      float s = ((a[0] + a[1]) + (a[2] + a[3])) + ((a[4] + a[5]) + (a[6] + a[7]));
      if (quar == 0) s += v[j] * dvec[(l * B_ + b) * N1_ + j];
      part[quar][j] = s;
    }
    __syncthreads();
    if (t < N1_) v[t] = (part[0][t] + part[1][t]) + (part[2][t] + part[3][t]);
    __syncthreads();
  }

  if (t < 64) {
    float val[4];
    int   idx[4];
#pragma unroll
    for (int c = 0; c < 4; ++c) {
      int n = t + c * 64;
      bool ok = (n < N1_ - 1);
      val[c] = ok ? v[n + 1] : -1e30f;
      idx[c] = ok ? n : (1 << 20);
    }
    for (int r = 0; r < R_; ++r) {
      float bv = val[0];
      int   bi = idx[0];
#pragma unroll
      for (int c = 1; c < 4; ++c)
        if (val[c] > bv || (val[c] == bv && idx[c] < bi)) { bv = val[c]; bi = idx[c]; }
#pragma unroll
      for (int o = 32; o; o >>= 1) {
        float ov = __shfl_xor(bv, o);
        int   oi = __shfl_xor(bi, o);
        if (ov > bv || (ov == bv && oi < bi)) { bv = ov; bi = oi; }
      }
      if (t == 0) gidx[b * R_ + r] = b * N1_ + bi + 1;
#pragma unroll
      for (int c = 0; c < 4; ++c)
        if (idx[c] == bi) val[c] = -1e30f;
    }
  }
}

// ---------------------------------------------------------------------------
// FAST split-bf16 GEMM, fused KV (600 tiles) + gathered-q (30 tiles).
// 128x128 tile, BK=32, 4 waves (2x2), 4x4 16x16x32 frags, 3 MFMA per pair.
// global_load_lds width=16, linear LDS dest, source chunk pre-swizzled
// c = c' ^ (row&7) [m173]; fragment ds_read_b128 at c' = lk ^ (lr&7).
// ---------------------------------------------------------------------------
__global__ __launch_bounds__(256) void gemm_kvq_fast(const ushort* __restrict__ xpack,
                                                     const ushort* __restrict__ wpack,
                                                     const int* __restrict__ gidx,
                                                     float* __restrict__ kvb,
                                                     float* __restrict__ qbuf) {
  __shared__ __attribute__((aligned(16))) ushort As[128 * 64];
  __shared__ __attribute__((aligned(16))) ushort Bs[128 * 64];
  int tid = threadIdx.x, lane = tid & 63, wid = tid >> 6;
  int wr = wid >> 1, wc = wid & 1;
  int lr = lane & 15, lk = lane >> 4;

  int bid = blockIdx.x;
  int bm, wrow0, ccol0, ldc, Mrows;
  float* C;
  bool gath;
  if (bid < 600) {
    bm = bid % 50; int bn = bid / 50;
    wrow0 = bn * 128; ccol0 = bn * 128; ldc = 1536; Mrows = M_TOK;
    C = kvb; gath = false;
  } else {
    int tq = bid - 600;
    bm = tq % 5; int bn = tq / 5;
    wrow0 = 1536 + bn * 128; ccol0 = bn * 128; ldc = 768; Mrows = 608;
    C = qbuf; gath = true;
  }

  const ushort* asrc[4];
  const ushort* bsrc[4];
  ushort* adst[4];
  ushort* bdst[4];
  int lrow = lane >> 3, cpr = lane & 7;
#pragma unroll
  for (int i = 0; i < 4; ++i) {
    int r_loc = wid * 32 + i * 8 + lrow;
    int c     = cpr ^ (r_loc & 7);
    int ga    = bm * 128 + r_loc; if (ga >= Mrows) ga = Mrows - 1;
    int arow  = gath ? gidx[ga] : ga;
    asrc[i] = xpack + (size_t)arow * 1536 + c * 8;
    bsrc[i] = wpack + (size_t)(wrow0 + r_loc) * 1536 + c * 8;
    adst[i] = &As[(wid * 32 + i * 8) * 64];
    bdst[i] = &Bs[(wid * 32 + i * 8) * 64];
  }

  int oh = (lk ^ (lr & 7)) * 8;
  int ol = oh ^ 32;

  f32x4 acc[4][4] = {};

#pragma unroll
  for (int i = 0; i < 4; ++i) { gl_lds16(asrc[i], adst[i]); gl_lds16(bsrc[i], bdst[i]); }

  for (int kb = 0; kb < 24; ++kb) {
    __syncthreads();
    short8 afh[4], afl[4], bfh[4], bfl[4];
#pragma unroll
    for (int m = 0; m < 4; ++m) {
      const ushort* rp = &As[(wr * 64 + m * 16 + lr) * 64];
      afh[m] = *(const short8*)(rp + oh);
      afl[m] = *(const short8*)(rp + ol);
    }
#pragma unroll
    for (int n = 0; n < 4; ++n) {
      const ushort* rp = &Bs[(wc * 64 + n * 16 + lr) * 64];
      bfh[n] = *(const short8*)(rp + oh);
      bfl[n] = *(const short8*)(rp + ol);
    }
    __syncthreads();
    if (kb < 23) {
#pragma unroll
      for (int i = 0; i < 4; ++i) {
        gl_lds16(asrc[i] + (kb + 1) * 64, adst[i]);
        gl_lds16(bsrc[i] + (kb + 1) * 64, bdst[i]);
      }
    }
#pragma unroll
    for (int m = 0; m < 4; ++m)
#pragma unroll
      for (int n = 0; n < 4; ++n) {
        acc[m][n] = __builtin_amdgcn_mfma_f32_16x16x32_bf16(afh[m], bfh[n], acc[m][n], 0, 0, 0);
        acc[m][n] = __builtin_amdgcn_mfma_f32_16x16x32_bf16(afh[m], bfl[n], acc[m][n], 0, 0, 0);
        acc[m][n] = __builtin_amdgcn_mfma_f32_16x16x32_bf16(afl[m], bfh[n], acc[m][n], 0, 0, 0);
      }
  }

#pragma unroll
  for (int m = 0; m < 4; ++m) {
    int row0 = bm * 128 + wr * 64 + m * 16 + (lane >> 4) * 4;
#pragma unroll
    for (int i = 0; i < 4; ++i) {
      int row = row0 + i;
      if (row < Mrows) {
#pragma unroll
        for (int n = 0; n < 4; ++n) {
          int col = ccol0 + wc * 64 + n * 16 + lr;
          C[(size_t)row * ldc + col] = acc[m][n][i];
        }
      }
    }
  }
}

// ---------------------------------------------------------------------------
// Slow (reg-staging) split-bf16 GEMM for the tiny proj matmul.
// ---------------------------------------------------------------------------
#define PK 40
template <int BM, int BN, int MF, int NF>
__global__ __launch_bounds__(256) void gemm_f32in(const float* __restrict__ A,
                                                  const float* __restrict__ W0,
                                                  const float* __restrict__ bias,
                                                  float* __restrict__ C,
                                                  int M, int K, int ldc) {
  __shared__ __attribute__((aligned(16))) ushort As[2][BM][PK];
  __shared__ __attribute__((aligned(16))) ushort Bs[2][BN][PK];
  constexpr int TPRA = 256 / BM;
  constexpr int EPTA = 32 / TPRA;
  constexpr int NA4  = EPTA / 4;
  constexpr int TPRB = 256 / BN;
  constexpr int EPTB = 32 / TPRB;
  constexpr int NB4  = EPTB / 4;

  int tid  = threadIdx.x;
  int lane = tid & 63, wid = tid >> 6;
  int wr = wid >> 1, wc = wid & 1;
  int lr = lane & 15, lk = lane >> 4;
  int bm = blockIdx.x, bn = blockIdx.y;

  int arow_s = tid / TPRA;
  int akoff  = (tid % TPRA) * EPTA;
  int ar = bm * BM + arow_s; if (ar >= M) ar = M - 1;
  const float* ap = A + (size_t)ar * K + akoff;

  int brow_s = tid / TPRB;
  int bkoff  = (tid % TPRB) * EPTB;
  int wrow   = bn * BN + brow_s;
  const float* wp = W0 + (size_t)wrow * K + bkoff;

  f32x4 acc[MF][NF] = {};

  float4 pa[NA4], pb[NB4];
#pragma unroll
  for (int u = 0; u < NA4; ++u) pa[u] = *(const float4*)(ap + u * 4);
#pragma unroll
  for (int u = 0; u < NB4; ++u) pb[u] = *(const float4*)(wp + u * 4);

  for (int k0 = 0; k0 < K; k0 += 32) {
#pragma unroll
    for (int u = 0; u < NA4; ++u) {
      ushort4 h, l; cvt4(pa[u], h, l);
      *(ushort4*)&As[0][arow_s][akoff + u * 4] = h;
      *(ushort4*)&As[1][arow_s][akoff + u * 4] = l;
    }
#pragma unroll
    for (int u = 0; u < NB4; ++u) {
      ushort4 h, l; cvt4(pb[u], h, l);
      *(ushort4*)&Bs[0][brow_s][bkoff + u * 4] = h;
      *(ushort4*)&Bs[1][brow_s][bkoff + u * 4] = l;
    }
    __syncthreads();

    int kn = k0 + 32;
    if (kn < K) {
#pragma unroll
      for (int u = 0; u < NA4; ++u) pa[u] = *(const float4*)(ap + kn + u * 4);
#pragma unroll
      for (int u = 0; u < NB4; ++u) pb[u] = *(const float4*)(wp + kn + u * 4);
    }

    short8 af[2][MF], bf[2][NF];
#pragma unroll
    for (int m = 0; m < MF; ++m) {
      af[0][m] = *(const short8*)&As[0][wr * (BM / 2) + m * 16 + lr][lk * 8];
      af[1][m] = *(const short8*)&As[1][wr * (BM / 2) + m * 16 + lr][lk * 8];
    }
#pragma unroll
    for (int n = 0; n < NF; ++n) {
      bf[0][n] = *(const short8*)&Bs[0][wc * (BN / 2) + n * 16 + lr][lk * 8];
      bf[1][n] = *(const short8*)&Bs[1][wc * (BN / 2) + n * 16 + lr][lk * 8];
    }
#pragma unroll
    for (int m = 0; m < MF; ++m)
#pragma unroll
      for (int n = 0; n < NF; ++n) {
        acc[m][n] = __builtin_amdgcn_mfma_f32_16x16x32_bf16(af[0][m], bf[0][n], acc[m][n], 0, 0, 0);
        acc[m][n] = __builtin_amdgcn_mfma_f32_16x16x32_bf16(af[0][m], bf[1][n], acc[m][n], 0, 0, 0);
        acc[m][n] = __builtin_amdgcn_mfma_f32_16x16x32_bf16(af[1][m], bf[0][n], acc[m][n], 0, 0, 0);
      }
    __syncthreads();
  }

#pragma unroll
  for (int m = 0; m < MF; ++m) {
    int row0 = bm * BM + wr * (BM / 2) + m * 16 + lk * 4;
#pragma unroll
    for (int i = 0; i < 4; ++i) {
      int row = row0 + i;
      if (row < M) {
#pragma unroll
        for (int n = 0; n < NF; ++n) {
          int col = bn * BN + wc * (BN / 2) + n * 16 + lr;
          float vv = acc[m][n][i];
          if (bias) vv += bias[col];
          C[(size_t)row * ldc + col] = vv;
        }
      }
    }
  }
}

// ---------------------------------------------------------------------------
// K5: per-(b,h) attention (f32).
// ---------------------------------------------------------------------------
__global__ __launch_bounds__(256) void k5_attn(const float* __restrict__ kvb,
                                               const float* __restrict__ qb,
                                               float* __restrict__ ctx) {
  int bh = blockIdx.x;
  int b = bh / H_, h = bh % H_;
  __shared__ float ks[N1_][68];
  __shared__ float qs[R_][64];
  __shared__ float sc[R_][200];
  __shared__ float rsum[R_];
  int t = threadIdx.x;
  int lane = t & 63, wid = t >> 6;

  const float* kbase = kvb + (size_t)b * N1_ * 1536 + h * 64;
  for (int n = wid; n < N1_; n += 4)
    ks[n][lane] = kbase[(size_t)n * 1536 + lane];
  const float* qrow = qb + (size_t)b * R_ * D_ + h * 64;
  for (int e = t; e < R_ * 64; e += 256) {
    int r = e >> 6, d = e & 63;
    qs[r][d] = qrow[(size_t)r * D_ + d];
  }
  __syncthreads();

  if (t < N1_) {
    float accr[R_];
#pragma unroll
    for (int r = 0; r < R_; ++r) accr[r] = 0.f;
#pragma unroll
    for (int d0 = 0; d0 < 4; ++d0) {
      float4 k0 = *(const float4*)&ks[t][d0 * 16 + 0];
      float4 k1 = *(const float4*)&ks[t][d0 * 16 + 4];
      float4 k2 = *(const float4*)&ks[t][d0 * 16 + 8];
      float4 k3 = *(const float4*)&ks[t][d0 * 16 + 12];
#pragma unroll
      for (int r = 0; r < R_; ++r) {
        float4 q0 = *(const float4*)&qs[r][d0 * 16 + 0];
        float4 q1 = *(const float4*)&qs[r][d0 * 16 + 4];
        float4 q2 = *(const float4*)&qs[r][d0 * 16 + 8];
        float4 q3 = *(const float4*)&qs[r][d0 * 16 + 12];
        accr[r] += k0.x * q0.x + k0.y * q0.y + k0.z * q0.z + k0.w * q0.w
                 + k1.x * q1.x + k1.y * q1.y + k1.z * q1.z + k1.w * q1.w
                 + k2.x * q2.x + k2.y * q2.y + k2.z * q2.z + k2.w * q2.w
                 + k3.x * q3.x + k3.y * q3.y + k3.z * q3.z + k3.w * q3.w;
      }
    }
#pragma unroll
    for (int r = 0; r < R_; ++r) sc[r][t] = accr[r] * 0.125f;
  }
  __syncthreads();

  for (int r = wid; r < R_; r += 4) {
    float x0 = sc[r][lane];
    float x1 = sc[r][lane + 64];
    float x2 = sc[r][lane + 128];
    bool ok3 = (lane + 192 < N1_);
    float x3 = ok3 ? sc[r][lane + 192] : -1e30f;
    float m = fmaxf(fmaxf(x0, x1), fmaxf(x2, x3));
#pragma unroll
    for (int o = 32; o; o >>= 1) m = fmaxf(m, __shfl_xor(m, o));
    float e0 = expf(x0 - m), e1 = expf(x1 - m), e2 = expf(x2 - m);
    float e3 = ok3 ? expf(x3 - m) : 0.f;
    float s = e0 + e1 + e2 + e3;
#pragma unroll
    for (int o = 32; o; o >>= 1) s += __shfl_xor(s, o);
    sc[r][lane] = e0; sc[r][lane + 64] = e1; sc[r][lane + 128] = e2;
    if (ok3) sc[r][lane + 192] = e3;
    if (lane == 0) rsum[r] = s;
  }
  __syncthreads();

  const float* vb = kvb + (size_t)b * N1_ * 1536 + 768 + h * 64 + lane;
  int r0 = wid, r1 = wid + 4, r2 = wid + 8, r3 = wid + 12, r4 = wid + 16;
  bool has4 = (r4 < R_);
  float a0 = 0.f, a1 = 0.f, a2 = 0.f, a3 = 0.f, a4 = 0.f;
#pragma unroll 4
  for (int n = 0; n < N1_; ++n) {
    float vv = vb[(size_t)n * 1536];
    a0 += sc[r0][n] * vv;
    a1 += sc[r1][n] * vv;
    a2 += sc[r2][n] * vv;
    a3 += sc[r3][n] * vv;
    if (has4) a4 += sc[r4][n] * vv;
  }
  float* cb = ctx + (size_t)(b * R_) * D_ + h * 64 + lane;
  cb[(size_t)r0 * D_] = a0 / rsum[r0];
  cb[(size_t)r1 * D_] = a1 / rsum[r1];
  cb[(size_t)r2 * D_] = a2 / rsum[r2];
  cb[(size_t)r3 * D_] = a3 / rsum[r3];
  if (has4) cb[(size_t)r4 * D_] = a4 / rsum[r4];
}

// ---------------------------------------------------------------------------
extern "C" void kernel_launch(void* const* d_in, const int* in_sizes, int n_in,
                              void* d_out, int out_size, void* d_ws, size_t ws_size,
                              hipStream_t stream) {
  const float* x      = (const float*)d_in[0];
  const float* attn   = (const float*)d_in[1];
  const float* q_w    = (const float*)d_in[2];
  const float* k_w    = (const float*)d_in[3];
  const float* v_w    = (const float*)d_in[4];
  const float* proj_w = (const float*)d_in[5];
  const float* proj_b = (const float*)d_in[6];
  float* out = (float*)d_out;

  char* w = (char*)d_ws;
  auto take = [&](size_t bytes) { char* p = w; w += (bytes + 255) & ~(size_t)255; return p; };
  float*  P     = (float*)take((size_t)L_ * B_ * N1_ * N1_ * 4);   // 59.6 MB
  float*  dvec  = (float*)take((size_t)L_ * B_ * N1_ * 4);
  int*    gidx  = (int*)take(B_ * R_ * 4);
  float*  kvb   = (float*)take((size_t)M_TOK * 1536 * 4);          // 38.7 MB
  float*  qbuf  = (float*)take((size_t)B_ * R_ * D_ * 4);
  float*  ctx   = (float*)take((size_t)B_ * R_ * D_ * 4);
  ushort* xpack = (ushort*)take((size_t)M_TOK * 1536 * 2);         // 19.4 MB
  ushort* wpack = (ushort*)take((size_t)2304 * 1536 * 2);          // 7.1 MB

  // 1) MEGA: vectorized k1 (HBM stream) + pack x/[k;v;q] (no LDS either side)
  hipLaunchKernelGGL(mega_k1_pack, dim3(K1_BLOCKS + PACK_BLOCKS), dim3(256), 0,
                     stream, attn, P, dvec, x, k_w, v_w, q_w, xpack, wpack);
  // 2) rollout chain (row 0) + top-19 indices
  hipLaunchKernelGGL(k2_chain_topk, dim3(B_), dim3(1024), 0, stream, P, dvec, gidx);
  // 3) fused fast GEMM: KV projection (600 tiles) + gathered-q (30 tiles)
  hipLaunchKernelGGL(gemm_kvq_fast, dim3(630), dim3(256), 0, stream,
                     xpack, wpack, gidx, kvb, qbuf);
  // 4) attention per (b,h)
  hipLaunchKernelGGL(k5_attn, dim3(B_ * H_), dim3(256), 0, stream, kvb, qbuf, ctx);
  // 5) output projection + bias -> d_out
  hipLaunchKernelGGL((gemm_f32in<64, 64, 2, 2>), dim3(10, 12), dim3(256), 0, stream,
                     ctx, proj_w, proj_b, out, B_ * R_, D_, D_);
}